// Round 1
// baseline (333.485 us; speedup 1.0000x reference)
//
#include <hip/hip_runtime.h>

// SpectralConv: B=8, H=256, W=256, C=64, modes 16x16, WIDTH=64, W_SCALE=0.02
// 5-stage truncated-DFT pipeline, all f32, twiddles via register recurrence.

#define NB 8
#define NH 256
#define NW 256
#define NC 64
#define NM 16
#define NO 64

// ---------------- Stage A: G[b][ky][h][i] = sum_w x[b,h,w,i] e^{-2pi i ky w/256}
// grid 512 = b(8) x hblk(64, 4 h each); 256 thr: i4 = t&15, hs = (t>>4)&3, kyq = t>>6 (4 ky each)
__global__ __launch_bounds__(256) void k_dft_w(const float* __restrict__ x,
                                               float* __restrict__ Gr, float* __restrict__ Gi) {
  __shared__ float2 cs[256];
  __shared__ float xs[4 * 1040];  // [hs][ww(16)][i(64)] row-stride 1040 (pad 16 floats)
  const int t = threadIdx.x;
  const int b = blockIdx.x >> 6;
  const int h0 = (blockIdx.x & 63) * 4;
  {
    float s, c;
    sincospif((float)t * (1.0f / 128.0f), &s, &c);
    cs[t] = make_float2(c, s);
  }
  const int i4 = t & 15;
  const int hs = (t >> 4) & 3;
  const int kyq = t >> 6;  // wave id; ky = kyq*4 + q

  float4 ar[4], ai[4];
#pragma unroll
  for (int q = 0; q < 4; ++q) { ar[q] = make_float4(0, 0, 0, 0); ai[q] = make_float4(0, 0, 0, 0); }
  float stepr[4], stepi[4], twr[4], twi[4];

  const float* xb = x + (((size_t)b * NH + h0) * NW) * NC;

  for (int ch = 0; ch < 16; ++ch) {
    const int w0 = ch * 16;
    __syncthreads();
#pragma unroll
    for (int r = 0; r < 4; ++r) {
      const float4* src = (const float4*)(xb + ((size_t)r * NW + w0) * NC);
      ((float4*)xs)[r * 260 + t] = src[t];
    }
    __syncthreads();
    if (ch == 0) {
#pragma unroll
      for (int q = 0; q < 4; ++q) {
        const int ky = kyq * 4 + q;
        float2 st = cs[ky];
        stepr[q] = st.x; stepi[q] = -st.y;  // e^{-2pi i ky/256}
      }
    }
#pragma unroll
    for (int q = 0; q < 4; ++q) {
      const int ky = kyq * 4 + q;
      float2 tv = cs[(ky * w0) & 255];
      twr[q] = tv.x; twi[q] = -tv.y;  // e^{-2pi i ky w0/256}
    }
#pragma unroll 4
    for (int ww = 0; ww < 16; ++ww) {
      float4 xv = ((const float4*)xs)[hs * 260 + ww * 16 + i4];
#pragma unroll
      for (int q = 0; q < 4; ++q) {
        ar[q].x += twr[q] * xv.x; ar[q].y += twr[q] * xv.y;
        ar[q].z += twr[q] * xv.z; ar[q].w += twr[q] * xv.w;
        ai[q].x += twi[q] * xv.x; ai[q].y += twi[q] * xv.y;
        ai[q].z += twi[q] * xv.z; ai[q].w += twi[q] * xv.w;
        float nr = twr[q] * stepr[q] - twi[q] * stepi[q];
        float ni = twr[q] * stepi[q] + twi[q] * stepr[q];
        twr[q] = nr; twi[q] = ni;
      }
    }
  }
  const int h = h0 + hs;
#pragma unroll
  for (int q = 0; q < 4; ++q) {
    const int ky = kyq * 4 + q;
    const size_t o = (((size_t)(b * NM + ky)) * NH + h) * NC + i4 * 4;
    *(float4*)(Gr + o) = ar[q];
    *(float4*)(Gi + o) = ai[q];
  }
}

// ---------------- Stage B: X[kx][ky][b][i] = sum_h e^{-2pi i kx h/256} (Gr + iGi)[b][ky][h][i]
// grid 256 = b(8) x ky(16) x ihalf(2); 256 thr: kx = t>>4, i2 = (t&15)*2
__global__ __launch_bounds__(256) void k_dft_h(const float* __restrict__ Gr, const float* __restrict__ Gi,
                                               float* __restrict__ Xr, float* __restrict__ Xi) {
  __shared__ float2 cs[256];
  __shared__ float gr[64 * 36];  // [hh][i(32)] pad to 36
  __shared__ float gi[64 * 36];
  const int t = threadIdx.x;
  const int b = blockIdx.x >> 5;
  const int ky = (blockIdx.x >> 1) & 15;
  const int ih = blockIdx.x & 1;
  {
    float s, c;
    sincospif((float)t * (1.0f / 128.0f), &s, &c);
    cs[t] = make_float2(c, s);
  }
  const int kx = t >> 4;
  const int i2 = (t & 15) * 2;
  float2 xr = make_float2(0, 0), xi = make_float2(0, 0);
  float str = 0.f, sti = 0.f, twr, twi;
  const float* grb = Gr + ((size_t)(b * NM + ky)) * NH * NC + ih * 32;
  const float* gib = Gi + ((size_t)(b * NM + ky)) * NH * NC + ih * 32;
  for (int ch = 0; ch < 4; ++ch) {
    const int h0 = ch * 64;
    __syncthreads();
    for (int r = 0; r < 2; ++r) {
      const int idx = r * 256 + t;       // 512 float4 loads = 64 rows x 8
      const int hh = idx >> 3, f4 = idx & 7;
      ((float4*)&gr[hh * 36])[f4] = *(const float4*)(grb + (size_t)(h0 + hh) * NC + f4 * 4);
      ((float4*)&gi[hh * 36])[f4] = *(const float4*)(gib + (size_t)(h0 + hh) * NC + f4 * 4);
    }
    __syncthreads();
    if (ch == 0) { float2 st = cs[kx]; str = st.x; sti = -st.y; }
    float2 tv = cs[(kx * h0) & 255];
    twr = tv.x; twi = -tv.y;
#pragma unroll 8
    for (int hh = 0; hh < 64; ++hh) {
      float2 g_r = *(const float2*)&gr[hh * 36 + i2];
      float2 g_i = *(const float2*)&gi[hh * 36 + i2];
      xr.x += twr * g_r.x - twi * g_i.x;
      xr.y += twr * g_r.y - twi * g_i.y;
      xi.x += twr * g_i.x + twi * g_r.x;
      xi.y += twr * g_i.y + twi * g_r.y;
      float nr = twr * str - twi * sti;
      float ni = twr * sti + twi * str;
      twr = nr; twi = ni;
    }
  }
  const size_t o = ((size_t)((kx * NM + ky) * NB + b)) * NC + ih * 32 + i2;
  *(float2*)(Xr + o) = xr;
  *(float2*)(Xi + o) = xi;
}

// ---------------- Stage C: om[b][kx][ky][o] = scale * sum_i X[kx][ky][b][i] * (wr + i wi)[kx][ky][i][o]
// grid 256 = kx(16) x ky(16); 256 thr: b = t>>5, o2 = (t&31)*2
__global__ __launch_bounds__(256) void k_mix(const float* __restrict__ Xr, const float* __restrict__ Xi,
                                             const float* __restrict__ w_real, const float* __restrict__ w_imag,
                                             float* __restrict__ omr, float* __restrict__ omi) {
  __shared__ float wr[64 * 64];
  __shared__ float wi[64 * 64];
  __shared__ float2 xc[8 * 64];
  const int t = threadIdx.x;
  const int kx = blockIdx.x >> 4;
  const int ky = blockIdx.x & 15;
  const size_t wbase = (size_t)(kx * NM + ky) * 4096;
  const float4* s1 = (const float4*)(w_real + wbase);
  const float4* s2 = (const float4*)(w_imag + wbase);
#pragma unroll
  for (int r = 0; r < 4; ++r) {
    ((float4*)wr)[r * 256 + t] = s1[r * 256 + t];
    ((float4*)wi)[r * 256 + t] = s2[r * 256 + t];
  }
  const size_t xbase = (size_t)(kx * NM + ky) * 512;
  for (int idx = t; idx < 512; idx += 256)
    xc[idx] = make_float2(Xr[xbase + idx], Xi[xbase + idx]);
  __syncthreads();
  const int b = t >> 5;
  const int o2 = (t & 31) * 2;
  float r0 = 0, i0 = 0, r1 = 0, i1 = 0;
#pragma unroll 8
  for (int i = 0; i < 64; ++i) {
    float2 xv = xc[b * 64 + i];
    float2 w_r = *(const float2*)&wr[i * 64 + o2];
    float2 w_i = *(const float2*)&wi[i * 64 + o2];
    r0 += xv.x * w_r.x - xv.y * w_i.x;
    i0 += xv.x * w_i.x + xv.y * w_r.x;
    r1 += xv.x * w_r.y - xv.y * w_i.y;
    i1 += xv.x * w_i.y + xv.y * w_r.y;
  }
  // fold W_SCALE, irfft Hermitian doubling c_ky, and 1/(H*W)
  const float scale = (ky == 0 ? 1.0f : 2.0f) * (0.02f / 65536.0f);
  const size_t ob = (size_t)((b * NM + kx) * NM + ky) * NO + o2;
  *(float2*)(omr + ob) = make_float2(r0 * scale, r1 * scale);
  *(float2*)(omi + ob) = make_float2(i0 * scale, i1 * scale);
}

// ---------------- Stage D: Zc[b][w][kx][o] = sum_ky om[b][kx][ky][o] e^{+2pi i ky w/256}
// grid 256 = b(8) x kx(16) x whalf(2); 256 thr: o = t&63, wv = t>>6 (32 w each)
__global__ __launch_bounds__(256) void k_idft_w(const float* __restrict__ omr, const float* __restrict__ omi,
                                                float2* __restrict__ Zc) {
  __shared__ float2 cs[256];
  const int t = threadIdx.x;
  const int b = blockIdx.x >> 5;
  const int kx = (blockIdx.x >> 1) & 15;
  const int wh = blockIdx.x & 1;
  {
    float s, c;
    sincospif((float)t * (1.0f / 128.0f), &s, &c);
    cs[t] = make_float2(c, s);
  }
  __syncthreads();
  const int o = t & 63;
  const int wv = t >> 6;
  float mr[16], mi[16];
  const size_t base = (size_t)(b * NM + kx) * (NM * NO) + o;
#pragma unroll
  for (int ky = 0; ky < 16; ++ky) {
    mr[ky] = omr[base + ky * NO];
    mi[ky] = omi[base + ky * NO];
  }
  for (int j = 0; j < 32; ++j) {
    const int w = wh * 128 + wv * 32 + j;
    const float2 st = cs[w];  // e^{+2pi i w/256}
    float twr = 1.0f, twi = 0.0f;
    float zr = 0.0f, zi = 0.0f;
#pragma unroll
    for (int ky = 0; ky < 16; ++ky) {
      zr += twr * mr[ky] - twi * mi[ky];
      zi += twr * mi[ky] + twi * mr[ky];
      float nr = twr * st.x - twi * st.y;
      float ni = twr * st.y + twi * st.x;
      twr = nr; twi = ni;
    }
    Zc[((size_t)(b * NW + w) * NM + kx) * NO + o] = make_float2(zr, zi);
  }
}

// ---------------- Stage E: out[b][h][w][o] = sum_kx Re( Zc[b][w][kx][o] e^{+2pi i kx h/256} )
// grid 2048 = b(8) x w(256); 256 thr: i4 = t&15 (4 o), h0 = (t>>4)*16 (16 h)
__global__ __launch_bounds__(256) void k_idft_h(const float2* __restrict__ Zc, float* __restrict__ out) {
  __shared__ float2 cs[256];
  __shared__ float2 zc[16 * 64];
  const int t = threadIdx.x;
  const int b = blockIdx.x >> 8;
  const int w = blockIdx.x & 255;
  {
    float s, c;
    sincospif((float)t * (1.0f / 128.0f), &s, &c);
    cs[t] = make_float2(c, s);
  }
  {
    const float4* src = (const float4*)(Zc + (size_t)(b * NW + w) * (NM * NO));
    ((float4*)zc)[t] = src[t];
    ((float4*)zc)[t + 256] = src[t + 256];
  }
  __syncthreads();
  const int i4 = t & 15;
  const int h0 = (t >> 4) * 16;
  float4 acc[16];
#pragma unroll
  for (int j = 0; j < 16; ++j) acc[j] = make_float4(0, 0, 0, 0);
  for (int kx = 0; kx < 16; ++kx) {
    const float4 za = ((const float4*)zc)[kx * 32 + i4 * 2];      // (zr0,zi0,zr1,zi1)
    const float4 zb = ((const float4*)zc)[kx * 32 + i4 * 2 + 1];  // (zr2,zi2,zr3,zi3)
    const float2 t0 = cs[(kx * h0) & 255];
    const float2 st = cs[kx];  // e^{+2pi i kx/256}
    float twr = t0.x, twi = t0.y;
#pragma unroll
    for (int j = 0; j < 16; ++j) {
      acc[j].x += twr * za.x - twi * za.y;
      acc[j].y += twr * za.z - twi * za.w;
      acc[j].z += twr * zb.x - twi * zb.y;
      acc[j].w += twr * zb.z - twi * zb.w;
      float nr = twr * st.x - twi * st.y;
      float ni = twr * st.y + twi * st.x;
      twr = nr; twi = ni;
    }
  }
  float* ob = out + (((size_t)b * NH + h0) * NW + w) * NO + i4 * 4;
#pragma unroll
  for (int j = 0; j < 16; ++j) {
    *(float4*)(ob + (size_t)j * (NW * NO)) = acc[j];
  }
}

extern "C" void kernel_launch(void* const* d_in, const int* in_sizes, int n_in,
                              void* d_out, int out_size, void* d_ws, size_t ws_size,
                              hipStream_t stream) {
  const float* x = (const float*)d_in[0];
  const float* w_real = (const float*)d_in[1];
  const float* w_imag = (const float*)d_in[2];
  float* out = (float*)d_out;
  char* ws = (char*)d_ws;

  // workspace layout (bytes): total 35,651,584
  float* Gr = (float*)(ws);                    //  8 MiB  [b][ky][h][i]
  float* Gi = (float*)(ws + 8388608);          //  8 MiB
  float* Xr = (float*)(ws + 16777216);         //  512 KiB [kx][ky][b][i]
  float* Xi = (float*)(ws + 17301504);         //  512 KiB
  float* omr = (float*)(ws + 17825792);        //  512 KiB [b][kx][ky][o]
  float* omi = (float*)(ws + 18350080);        //  512 KiB
  float2* Zc = (float2*)(ws + 18874368);       //  16 MiB  [b][w][kx][o]

  k_dft_w<<<dim3(512), dim3(256), 0, stream>>>(x, Gr, Gi);
  k_dft_h<<<dim3(256), dim3(256), 0, stream>>>(Gr, Gi, Xr, Xi);
  k_mix<<<dim3(256), dim3(256), 0, stream>>>(Xr, Xi, w_real, w_imag, omr, omi);
  k_idft_w<<<dim3(256), dim3(256), 0, stream>>>(omr, omi, Zc);
  k_idft_h<<<dim3(2048), dim3(256), 0, stream>>>(Zc, out);
}

// Round 2
// 311.512 us; speedup vs baseline: 1.0705x; 1.0705x over previous
//
#include <hip/hip_runtime.h>

// SpectralConv: B=8, H=256, W=256, C=64, modes 16x16, WIDTH=64, W_SCALE=0.02
// 5-stage truncated-DFT pipeline, f32, twiddles via register recurrence.
// Round 2: occupancy fix — every stage >= 4 blocks/CU, no barriers in hot loops.

#define NB 8
#define NH 256
#define NW 256
#define NC 64
#define NM 16
#define NO 64

// ---------------- Stage A: G[b][ky][h][i] = sum_w x[b,h,w,i] e^{-2pi i ky w/256}
// grid 1024 = b(8) x h2(128); 256 thr: i4 = t&15, hs = (t>>4)&1, kyq = t>>5 (2 ky each)
__global__ __launch_bounds__(256) void k_dft_w(const float* __restrict__ x,
                                               float* __restrict__ Gr, float* __restrict__ Gi) {
  __shared__ float2 cs[256];
  const int t = threadIdx.x;
  {
    float s, c;
    sincospif((float)t * (1.0f / 128.0f), &s, &c);
    cs[t] = make_float2(c, s);
  }
  __syncthreads();
  const int b = blockIdx.x >> 7;
  const int h2 = blockIdx.x & 127;
  const int i4 = t & 15;
  const int hs = (t >> 4) & 1;
  const int kyq = t >> 5;  // 0..7
  const int ky0 = kyq * 2, ky1 = ky0 + 1;
  const int h = h2 * 2 + hs;
  const float* xp = x + ((size_t)(b * NH + h) * NW) * NC + i4 * 4;

  float4 ar0 = {0, 0, 0, 0}, ai0 = {0, 0, 0, 0}, ar1 = {0, 0, 0, 0}, ai1 = {0, 0, 0, 0};
  const float2 s0 = cs[ky0], s1 = cs[ky1];
  const float s0r = s0.x, s0i = -s0.y, s1r = s1.x, s1i = -s1.y;

  for (int wc = 0; wc < 8; ++wc) {
    const int w0 = wc * 32;
    const float2 v0 = cs[(ky0 * w0) & 255], v1 = cs[(ky1 * w0) & 255];
    float t0r = v0.x, t0i = -v0.y, t1r = v1.x, t1i = -v1.y;
#pragma unroll 8
    for (int w = 0; w < 32; ++w) {
      const float4 xv = *(const float4*)(xp + (size_t)(w0 + w) * NC);
      ar0.x += t0r * xv.x; ar0.y += t0r * xv.y; ar0.z += t0r * xv.z; ar0.w += t0r * xv.w;
      ai0.x += t0i * xv.x; ai0.y += t0i * xv.y; ai0.z += t0i * xv.z; ai0.w += t0i * xv.w;
      ar1.x += t1r * xv.x; ar1.y += t1r * xv.y; ar1.z += t1r * xv.z; ar1.w += t1r * xv.w;
      ai1.x += t1i * xv.x; ai1.y += t1i * xv.y; ai1.z += t1i * xv.z; ai1.w += t1i * xv.w;
      float n0r = t0r * s0r - t0i * s0i, n0i = t0r * s0i + t0i * s0r;
      float n1r = t1r * s1r - t1i * s1i, n1i = t1r * s1i + t1i * s1r;
      t0r = n0r; t0i = n0i; t1r = n1r; t1i = n1i;
    }
  }
  const size_t g0 = ((size_t)(b * NM + ky0) * NH + h) * NC + i4 * 4;
  const size_t g1 = ((size_t)(b * NM + ky1) * NH + h) * NC + i4 * 4;
  *(float4*)(Gr + g0) = ar0; *(float4*)(Gi + g0) = ai0;
  *(float4*)(Gr + g1) = ar1; *(float4*)(Gi + g1) = ai1;
}

// ---------------- Stage B: Xp[hc][kx][ky][b][i] = sum_{h in chunk} e^{-2pi i kx h/256} G[b][ky][h][i]
// grid 1024 = b(8) x ky(16) x hc(8); 256 thr: i4 = t&15, kx = t>>4
__global__ __launch_bounds__(256) void k_dft_h(const float* __restrict__ Gr, const float* __restrict__ Gi,
                                               float* __restrict__ Xpr, float* __restrict__ Xpi) {
  __shared__ float2 cs[256];
  __shared__ float gr[32 * 64];
  __shared__ float gi[32 * 64];
  const int t = threadIdx.x;
  {
    float s, c;
    sincospif((float)t * (1.0f / 128.0f), &s, &c);
    cs[t] = make_float2(c, s);
  }
  const int b = blockIdx.x >> 7;
  const int ky = (blockIdx.x >> 3) & 15;
  const int hc = blockIdx.x & 7;
  const float* grs = Gr + ((size_t)(b * NM + ky) * NH + hc * 32) * NC;
  const float* gis = Gi + ((size_t)(b * NM + ky) * NH + hc * 32) * NC;
#pragma unroll
  for (int r = 0; r < 2; ++r) {
    ((float4*)gr)[r * 256 + t] = ((const float4*)grs)[r * 256 + t];
    ((float4*)gi)[r * 256 + t] = ((const float4*)gis)[r * 256 + t];
  }
  __syncthreads();
  const int i4 = t & 15;
  const int kx = t >> 4;
  float4 xr = {0, 0, 0, 0}, xi = {0, 0, 0, 0};
  const float2 sv = cs[kx];
  const float str = sv.x, sti = -sv.y;
  const float2 tv = cs[(kx * hc * 32) & 255];
  float twr = tv.x, twi = -tv.y;
#pragma unroll 4
  for (int hh = 0; hh < 32; ++hh) {
    const float4 g_r = *(const float4*)&gr[hh * 64 + i4 * 4];
    const float4 g_i = *(const float4*)&gi[hh * 64 + i4 * 4];
    xr.x += twr * g_r.x - twi * g_i.x;
    xr.y += twr * g_r.y - twi * g_i.y;
    xr.z += twr * g_r.z - twi * g_i.z;
    xr.w += twr * g_r.w - twi * g_i.w;
    xi.x += twr * g_i.x + twi * g_r.x;
    xi.y += twr * g_i.y + twi * g_r.y;
    xi.z += twr * g_i.z + twi * g_r.z;
    xi.w += twr * g_i.w + twi * g_r.w;
    const float nr = twr * str - twi * sti;
    const float ni = twr * sti + twi * str;
    twr = nr; twi = ni;
  }
  const size_t o = ((size_t)((hc * NM + kx) * NM + ky) * NB + b) * NC + i4 * 4;
  *(float4*)(Xpr + o) = xr;
  *(float4*)(Xpi + o) = xi;
}

// ---------------- Stage C: om[b][kx][ky][o] = scale * sum_i (sum_hc Xp) * (wr + i wi)[kx][ky][i][o]
// grid 512 = kx(16) x ky(16) x oh(2); 256 thr: o = t&31, b = t>>5
__global__ __launch_bounds__(256) void k_mix(const float* __restrict__ Xpr, const float* __restrict__ Xpi,
                                             const float* __restrict__ w_real, const float* __restrict__ w_imag,
                                             float2* __restrict__ om) {
  __shared__ float wr_s[64 * 32];
  __shared__ float wi_s[64 * 32];
  __shared__ float2 xc[8 * 64];
  const int t = threadIdx.x;
  const int kx = blockIdx.x >> 5;
  const int ky = (blockIdx.x >> 1) & 15;
  const int oh = blockIdx.x & 1;
  const size_t wb = (size_t)(kx * NM + ky) * 4096 + oh * 32;
#pragma unroll
  for (int r = 0; r < 2; ++r) {
    const int idx = r * 256 + t;  // 0..511
    const int i = idx >> 3, f = idx & 7;
    *(float4*)&wr_s[i * 32 + f * 4] = *(const float4*)(w_real + wb + (size_t)i * 64 + f * 4);
    *(float4*)&wi_s[i * 32 + f * 4] = *(const float4*)(w_imag + wb + (size_t)i * 64 + f * 4);
  }
#pragma unroll
  for (int r = 0; r < 2; ++r) {
    const int idx = r * 256 + t;  // idx = b*64 + i
    const size_t base = (size_t)(kx * NM + ky) * 512 + idx;
    float sr = 0.f, si = 0.f;
#pragma unroll
    for (int hc = 0; hc < 8; ++hc) {
      sr += Xpr[base + (size_t)hc * 131072];
      si += Xpi[base + (size_t)hc * 131072];
    }
    xc[idx] = make_float2(sr, si);
  }
  __syncthreads();
  const int o = t & 31;
  const int b = t >> 5;
  float r0 = 0.f, i0 = 0.f;
#pragma unroll 8
  for (int i = 0; i < 64; ++i) {
    const float2 xv = xc[b * 64 + i];
    const float wrv = wr_s[i * 32 + o];
    const float wiv = wi_s[i * 32 + o];
    r0 += xv.x * wrv - xv.y * wiv;
    i0 += xv.x * wiv + xv.y * wrv;
  }
  const float sc = (ky == 0 ? 1.0f : 2.0f) * (0.02f / 65536.0f);
  om[((size_t)(b * NM + kx) * NM + ky) * NO + oh * 32 + o] = make_float2(r0 * sc, i0 * sc);
}

// ---------------- Stage D: Zc[b][w][kx][o] = sum_ky om[b][kx][ky][o] e^{+2pi i ky w/256}
// grid 1024 = b(8) x kx(16) x wq(8); 256 thr: o = t&63, wg = t>>6 (8 w each)
__global__ __launch_bounds__(256) void k_idft_w(const float2* __restrict__ om, float2* __restrict__ Zc) {
  __shared__ float2 cs[256];
  const int t = threadIdx.x;
  {
    float s, c;
    sincospif((float)t * (1.0f / 128.0f), &s, &c);
    cs[t] = make_float2(c, s);
  }
  __syncthreads();
  const int b = blockIdx.x >> 7;
  const int kx = (blockIdx.x >> 3) & 15;
  const int wq = blockIdx.x & 7;
  const int o = t & 63;
  const int wg = t >> 6;
  float mr[16], mi[16];
  const size_t base = ((size_t)(b * NM + kx) * NM) * NO + o;
#pragma unroll
  for (int ky = 0; ky < NM; ++ky) {
    const float2 v = om[base + ky * NO];
    mr[ky] = v.x; mi[ky] = v.y;
  }
#pragma unroll
  for (int j = 0; j < 8; ++j) {
    const int w = wq * 32 + wg * 8 + j;
    const float2 st = cs[w];
    float twr = 1.0f, twi = 0.0f;
    float zr = 0.0f, zi = 0.0f;
#pragma unroll
    for (int ky = 0; ky < NM; ++ky) {
      zr += twr * mr[ky] - twi * mi[ky];
      zi += twr * mi[ky] + twi * mr[ky];
      const float nr = twr * st.x - twi * st.y;
      const float ni = twr * st.y + twi * st.x;
      twr = nr; twi = ni;
    }
    Zc[((size_t)(b * NW + w) * NM + kx) * NO + o] = make_float2(zr, zi);
  }
}

// ---------------- Stage E: out[b][h][w][o] = sum_kx Re( Zc[b][w][kx][o] e^{+2pi i kx h/256} )
// grid 4096 = b(8) x w(256) x hh(2); 256 thr: i4 = t&15 (4 o), hg = t>>4 (8 h each)
__global__ __launch_bounds__(256) void k_idft_h(const float2* __restrict__ Zc, float* __restrict__ out) {
  __shared__ float2 cs[256];
  __shared__ float zre[16 * 64];
  __shared__ float zim[16 * 64];
  const int t = threadIdx.x;
  {
    float s, c;
    sincospif((float)t * (1.0f / 128.0f), &s, &c);
    cs[t] = make_float2(c, s);
  }
  const int b = blockIdx.x >> 9;
  const int w = (blockIdx.x >> 1) & 255;
  const int hh = blockIdx.x & 1;
  const float4* src = (const float4*)(Zc + (size_t)(b * NW + w) * (NM * NO));
#pragma unroll
  for (int r = 0; r < 2; ++r) {
    const int idx = r * 256 + t;  // float4 = 2 complex
    const float4 v = src[idx];
    ((float2*)zre)[idx] = make_float2(v.x, v.z);
    ((float2*)zim)[idx] = make_float2(v.y, v.w);
  }
  __syncthreads();
  const int i4 = t & 15;
  const int hg = t >> 4;
  const int h0 = hh * 128 + hg * 8;
  float4 acc[8];
#pragma unroll
  for (int j = 0; j < 8; ++j) acc[j] = make_float4(0, 0, 0, 0);
#pragma unroll 4
  for (int kx = 0; kx < 16; ++kx) {
    const float4 zr4 = ((const float4*)zre)[kx * 16 + i4];
    const float4 zi4 = ((const float4*)zim)[kx * 16 + i4];
    const float2 t0 = cs[(kx * h0) & 255];
    const float2 st = cs[kx];
    float twr = t0.x, twi = t0.y;
#pragma unroll
    for (int j = 0; j < 8; ++j) {
      acc[j].x += twr * zr4.x - twi * zi4.x;
      acc[j].y += twr * zr4.y - twi * zi4.y;
      acc[j].z += twr * zr4.z - twi * zi4.z;
      acc[j].w += twr * zr4.w - twi * zi4.w;
      const float nr = twr * st.x - twi * st.y;
      const float ni = twr * st.y + twi * st.x;
      twr = nr; twi = ni;
    }
  }
  float* ob = out + (((size_t)(b * NH) + h0) * NW + w) * NO + i4 * 4;
#pragma unroll
  for (int j = 0; j < 8; ++j) {
    *(float4*)(ob + (size_t)j * (NW * NO)) = acc[j];
  }
}

extern "C" void kernel_launch(void* const* d_in, const int* in_sizes, int n_in,
                              void* d_out, int out_size, void* d_ws, size_t ws_size,
                              hipStream_t stream) {
  const float* x = (const float*)d_in[0];
  const float* w_real = (const float*)d_in[1];
  const float* w_imag = (const float*)d_in[2];
  float* out = (float*)d_out;
  char* ws = (char*)d_ws;

  // workspace layout (bytes), total 26,214,400 (~25 MiB):
  // Zc overlaps Gr/Gi (G dead after stage B; Zc written in stage D).
  float* Gr = (float*)(ws);                 // 8 MiB  [b][ky][h][i]
  float* Gi = (float*)(ws + 8388608);       // 8 MiB
  float* Xpr = (float*)(ws + 16777216);     // 4 MiB  [hc][kx][ky][b][i]
  float* Xpi = (float*)(ws + 20971520);     // 4 MiB
  float2* om = (float2*)(ws + 25165824);    // 1 MiB  [b][kx][ky][o]
  float2* Zc = (float2*)(ws);               // 16 MiB [b][w][kx][o] (aliases Gr/Gi)

  k_dft_w<<<dim3(1024), dim3(256), 0, stream>>>(x, Gr, Gi);
  k_dft_h<<<dim3(1024), dim3(256), 0, stream>>>(Gr, Gi, Xpr, Xpi);
  k_mix<<<dim3(512), dim3(256), 0, stream>>>(Xpr, Xpi, w_real, w_imag, om);
  k_idft_w<<<dim3(1024), dim3(256), 0, stream>>>(om, Zc);
  k_idft_h<<<dim3(4096), dim3(256), 0, stream>>>(Zc, out);
}